// Round 4
// baseline (661.527 us; speedup 1.0000x reference)
//
#include <hip/hip_runtime.h>
#include <math.h>

// Problem constants
static constexpr int Bn    = 4;
static constexpr int Cc    = 128;
static constexpr int Hh    = 128;
static constexpr int Wb    = 128;
static constexpr int Nn    = Hh * Wb;      // 16384
static constexpr int HEADS = 8;
static constexpr int CHh   = 16;
static constexpr int HID   = 340;
static constexpr int HID2  = 680;
static constexpr int NS    = 64;
static constexpr int MPAD  = 704;          // pin M padded (680 -> 44*16)
static constexpr int KPAD2 = 352;          // pout K padded (340 -> 11*32)

typedef unsigned short ushort_t;
typedef __attribute__((ext_vector_type(8))) short short8;
typedef __attribute__((ext_vector_type(4))) float f32x4;

__device__ __forceinline__ ushort_t f2bf(float f) {
    unsigned u = __float_as_uint(f);
    return (ushort_t)((u + 0x7FFFu + ((u >> 16) & 1u)) >> 16);   // RNE
}
__device__ __forceinline__ float bf2f(ushort_t h) {
    return __uint_as_float(((unsigned)h) << 16);
}

// fast tanh: tanh(x) = 1 - 2/(e^{2|x|}+1), sign-restored.
__device__ __forceinline__ float fast_tanh(float x) {
    float a = fabsf(x);
    a = fminf(a, 12.0f);
    float e = __expf(2.0f * a);
    float r = 1.0f - 2.0f * __builtin_amdgcn_rcpf(e + 1.0f);
    return x < 0.0f ? -r : r;
}

// ---------------------------------------------------------------------------
// IEL v6 LDS helpers. Layouts (stride 144 floats = 576 B, rows 16B-aligned):
//   ts[20][144]: ts[i][c] = t(gy0-2+i, c-8), data c = 8..135, zeros elsewhere.
//   us[18][144]: us[i][c] = u(gy0-1+i, c-5), u = conv3x3(t,wa) with zero-pad,
//                valid (possibly zero-forced) for c = 4..135.
// All LDS accesses are 16B-aligned b128 with lane-consecutive addresses.
// ---------------------------------------------------------------------------
__device__ __forceinline__ void iel6_stage(float (*ts)[144], const ushort_t* __restrict__ tp,
                                           int gy0, int tid) {
    for (int idx = tid; idx < 360; idx += 256) {
        int i = idx / 18;          // row 0..19, gy = gy0-2+i
        int j = idx - i * 18;      // strip 0..17, cols c = 8j..8j+7
        int gy = gy0 - 2 + i;
        float v[8];
        if (j >= 1 && j <= 16 && gy >= 0 && gy < Hh) {
            uint4 u = *(const uint4*)(tp + gy * Wb + (j - 1) * 8);
            v[0] = bf2f((ushort_t)(u.x & 0xFFFF)); v[1] = bf2f((ushort_t)(u.x >> 16));
            v[2] = bf2f((ushort_t)(u.y & 0xFFFF)); v[3] = bf2f((ushort_t)(u.y >> 16));
            v[4] = bf2f((ushort_t)(u.z & 0xFFFF)); v[5] = bf2f((ushort_t)(u.z >> 16));
            v[6] = bf2f((ushort_t)(u.w & 0xFFFF)); v[7] = bf2f((ushort_t)(u.w >> 16));
        } else {
            #pragma unroll
            for (int k = 0; k < 8; ++k) v[k] = 0.f;
        }
        float4 a; a.x = v[0]; a.y = v[1]; a.z = v[2]; a.w = v[3];
        float4 bq; bq.x = v[4]; bq.y = v[5]; bq.z = v[6]; bq.w = v[7];
        *(float4*)&ts[i][8 * j]     = a;
        *(float4*)&ts[i][8 * j + 4] = bq;
    }
}

// u = conv3x3(t, wa), zero-padded. Strip k writes us cols 8k..8k+7
// (gx = 8k-5+p). Reads ts[i+dy][8k .. 8k+11] (3 aligned b128).
// Index map: e[j] = ts[.][8k+j] <-> t gx = 8k+j-8; want gx = 8k-5+p+dx-1
//   -> j = p+dx+2 (p+2..p+4).
__device__ __forceinline__ void iel6_ustage(const float (*ts)[144], float (*us)[144],
                                            const float* __restrict__ wa9,
                                            int gy0, int tid) {
    float wa[9];
    #pragma unroll
    for (int k = 0; k < 9; ++k) wa[k] = wa9[k];
    for (int idx = tid; idx < 306; idx += 256) {
        int i = idx / 17;          // 0..17, gy = gy0-1+i
        int k = idx - i * 17;      // strip 0..16
        int gy = gy0 - 1 + i;
        float a[8] = {0.f, 0.f, 0.f, 0.f, 0.f, 0.f, 0.f, 0.f};
        if (gy >= 0 && gy < Hh) {
            #pragma unroll
            for (int dy = 0; dy < 3; ++dy) {
                const float* row = &ts[i + dy][8 * k];
                float4 e0 = *(const float4*)row;
                float4 e1 = *(const float4*)(row + 4);
                float4 e2 = *(const float4*)(row + 8);
                float e[12] = {e0.x, e0.y, e0.z, e0.w, e1.x, e1.y, e1.z, e1.w,
                               e2.x, e2.y, e2.z, e2.w};
                float w0 = wa[dy * 3], w1 = wa[dy * 3 + 1], w2 = wa[dy * 3 + 2];
                #pragma unroll
                for (int p = 0; p < 8; ++p)
                    a[p] += w0 * e[p + 2] + w1 * e[p + 3] + w2 * e[p + 4];
            }
            // exact zero-padding of u at gx outside [0,127]
            #pragma unroll
            for (int p = 0; p < 8; ++p) {
                int gx = 8 * k - 5 + p;
                if (gx < 0 || gx > 127) a[p] = 0.f;
            }
        }
        float4 o0; o0.x = a[0]; o0.y = a[1]; o0.z = a[2]; o0.w = a[3];
        float4 o1; o1.x = a[4]; o1.y = a[5]; o1.z = a[6]; o1.w = a[7];
        *(float4*)&us[i][8 * k]     = o0;
        *(float4*)&us[i][8 * k + 4] = o1;
    }
}

// outer conv3x3(u, wb) + center; res[p] = fast_tanh(s[p]) + u_center[p].
// Thread (r,s): output row gy0+r, cols 8s..8s+7.
// e[j] = us[.][x0+4+j] <-> u gx = x0+j-1; want gx = x0+p+dx-1 -> j = p+dx.
__device__ __forceinline__ void iel6_outer(const float (*us)[144],
                                           const float* __restrict__ wb9,
                                           int r, int s, float res[8]) {
    float wb[9];
    #pragma unroll
    for (int k = 0; k < 9; ++k) wb[k] = wb9[k];
    int x0 = 8 * s;
    float aa[8] = {0.f, 0.f, 0.f, 0.f, 0.f, 0.f, 0.f, 0.f};
    float ctr[8];
    #pragma unroll
    for (int dy = 0; dy < 3; ++dy) {
        const float* row = &us[r + dy][x0 + 4];
        float4 e0 = *(const float4*)row;
        float4 e1 = *(const float4*)(row + 4);
        float4 e2 = *(const float4*)(row + 8);
        float e[12] = {e0.x, e0.y, e0.z, e0.w, e1.x, e1.y, e1.z, e1.w,
                       e2.x, e2.y, e2.z, e2.w};
        float w0 = wb[dy * 3], w1 = wb[dy * 3 + 1], w2 = wb[dy * 3 + 2];
        #pragma unroll
        for (int p = 0; p < 8; ++p)
            aa[p] += w0 * e[p] + w1 * e[p + 1] + w2 * e[p + 2];
        if (dy == 1) {
            #pragma unroll
            for (int p = 0; p < 8; ++p) ctr[p] = e[p + 1];
        }
    }
    #pragma unroll
    for (int p = 0; p < 8; ++p) res[p] = fast_tanh(aa[p]) + ctr[p];
}

// ---------------------------------------------------------------------------
// LayerNorm over channel axis, f32 out (tier-2). grid: (Nn/256, 1, Bt).
// ---------------------------------------------------------------------------
__global__ __launch_bounds__(256) void ln_kernel(const float* __restrict__ in,
                                                 const float* __restrict__ w,
                                                 const float* __restrict__ bias,
                                                 float* __restrict__ out) {
    int p = blockIdx.x * 256 + threadIdx.x;
    int b = blockIdx.z;
    const float* ib = in + (size_t)b * Cc * Nn + p;
    float s = 0.f, s2 = 0.f;
    #pragma unroll 8
    for (int c = 0; c < Cc; ++c) {
        float v = ib[(size_t)c * Nn];
        s += v; s2 += v * v;
    }
    float mean = s * (1.0f / Cc);
    float var  = s2 * (1.0f / Cc) - mean * mean;
    float inv  = 1.0f / sqrtf(var + 1e-6f);
    float* ob = out + (size_t)b * Cc * Nn + p;
    #pragma unroll 8
    for (int c = 0; c < Cc; ++c) {
        float v = ib[(size_t)c * Nn];
        ob[(size_t)c * Nn] = w[c] * ((v - mean) * inv) + bias[c];
    }
}

// LayerNorm writing bf16 (feeds MFMA GEMMs).
__global__ __launch_bounds__(256) void ln_bf16_kernel(const float* __restrict__ in,
                                                      const float* __restrict__ w,
                                                      const float* __restrict__ bias,
                                                      ushort_t* __restrict__ out) {
    int p = blockIdx.x * 256 + threadIdx.x;
    int b = blockIdx.z;
    const float* ib = in + (size_t)b * Cc * Nn + p;
    float s = 0.f, s2 = 0.f;
    #pragma unroll 8
    for (int c = 0; c < Cc; ++c) {
        float v = ib[(size_t)c * Nn];
        s += v; s2 += v * v;
    }
    float mean = s * (1.0f / Cc);
    float var  = s2 * (1.0f / Cc) - mean * mean;
    float inv  = 1.0f / sqrtf(var + 1e-6f);
    ushort_t* ob = out + (size_t)b * Cc * Nn + p;
    #pragma unroll 8
    for (int c = 0; c < Cc; ++c) {
        float v = ib[(size_t)c * Nn];
        ob[(size_t)c * Nn] = f2bf(w[c] * ((v - mean) * inv) + bias[c]);
    }
}

// ---------------------------------------------------------------------------
// Weight conversion f32 -> bf16 (+ padding variants).
// ---------------------------------------------------------------------------
__global__ __launch_bounds__(256) void wconv_pad_rows_kernel(const float* __restrict__ w,
                                                             ushort_t* __restrict__ o,
                                                             int rows, int K) {
    int idx = blockIdx.x * 256 + threadIdx.x;
    int r = idx / K, k = idx - r * K;
    o[idx] = (r < rows) ? f2bf(w[(size_t)r * K + k]) : (ushort_t)0;
}
__global__ __launch_bounds__(256) void wconv_pad_cols_kernel(const float* __restrict__ w,
                                                             ushort_t* __restrict__ o,
                                                             int K, int Kp) {
    int idx = blockIdx.x * 256 + threadIdx.x;
    int r = idx / Kp, k = idx - r * Kp;
    o[idx] = (k < K) ? f2bf(w[(size_t)r * K + k]) : (ushort_t)0;
}

// Zero a small f32 buffer (for ssq atomics).
__global__ __launch_bounds__(256) void zero_f32_kernel(float* __restrict__ p, int n) {
    int i = blockIdx.x * 256 + threadIdx.x;
    if (i < n) p[i] = 0.f;
}

// ---------------------------------------------------------------------------
// bf16 MFMA GEMM v2: out[b,co,p] = sum_ci W[co,ci] * Z[b,ci,p]
// ---------------------------------------------------------------------------
__global__ __launch_bounds__(256) void gemm_bf16_kernel(const ushort_t* __restrict__ Zh,
                                                        const ushort_t* __restrict__ Wh,
                                                        const float* __restrict__ bias,
                                                        const float* __restrict__ res,
                                                        float* outf,
                                                        ushort_t* outh,
                                                        int Cin, int Kpad, int Mreal,
                                                        int act) {
    const int b    = blockIdx.z;
    const int px0  = blockIdx.x * 128;
    const int co0  = blockIdx.y * 64;
    const int tid  = threadIdx.x;
    const int wv   = tid >> 6;
    const int lane = tid & 63;
    const int n    = lane & 15;
    const int q    = lane >> 4;

    __shared__ ushort_t Bl[128][40];

    const ushort_t* Zb = Zh + (size_t)b * Cin * Nn;

    f32x4 acc[4][2];
    #pragma unroll
    for (int i = 0; i < 4; ++i)
        #pragma unroll
        for (int j = 0; j < 2; ++j) acc[i][j] = (f32x4){0.f, 0.f, 0.f, 0.f};

    for (int k0 = 0; k0 < Kpad; k0 += 32) {
        {
            int r = tid >> 3;        // k row 0..31
            int s = tid & 7;         // 16-px chunk
            int ci = k0 + r;
            ushort_t tmp[16];
            if (ci < Cin) {
                const ushort_t* src = Zb + (size_t)ci * Nn + px0 + s * 16;
                uint4 v0 = *(const uint4*)src;
                uint4 v1 = *(const uint4*)(src + 8);
                tmp[0]  = (ushort_t)(v0.x & 0xFFFF); tmp[1]  = (ushort_t)(v0.x >> 16);
                tmp[2]  = (ushort_t)(v0.y & 0xFFFF); tmp[3]  = (ushort_t)(v0.y >> 16);
                tmp[4]  = (ushort_t)(v0.z & 0xFFFF); tmp[5]  = (ushort_t)(v0.z >> 16);
                tmp[6]  = (ushort_t)(v0.w & 0xFFFF); tmp[7]  = (ushort_t)(v0.w >> 16);
                tmp[8]  = (ushort_t)(v1.x & 0xFFFF); tmp[9]  = (ushort_t)(v1.x >> 16);
                tmp[10] = (ushort_t)(v1.y & 0xFFFF); tmp[11] = (ushort_t)(v1.y >> 16);
                tmp[12] = (ushort_t)(v1.z & 0xFFFF); tmp[13] = (ushort_t)(v1.z >> 16);
                tmp[14] = (ushort_t)(v1.w & 0xFFFF); tmp[15] = (ushort_t)(v1.w >> 16);
            } else {
                #pragma unroll
                for (int i = 0; i < 16; ++i) tmp[i] = 0;
            }
            #pragma unroll
            for (int i = 0; i < 16; ++i) Bl[s * 16 + i][r] = tmp[i];
        }
        __syncthreads();

        short8 bfrag[2];
        #pragma unroll
        for (int px16 = 0; px16 < 2; ++px16)
            bfrag[px16] = *(const short8*)&Bl[wv * 32 + px16 * 16 + n][q * 8];
        #pragma unroll
        for (int mt = 0; mt < 4; ++mt) {
            const ushort_t* wp = Wh + (size_t)(co0 + mt * 16 + n) * Kpad + k0 + q * 8;
            short8 afrag = *(const short8*)wp;
            #pragma unroll
            for (int px16 = 0; px16 < 2; ++px16)
                acc[mt][px16] = __builtin_amdgcn_mfma_f32_16x16x32_bf16(
                    afrag, bfrag[px16], acc[mt][px16], 0, 0, 0);
        }
        __syncthreads();
    }

    #pragma unroll
    for (int px16 = 0; px16 < 2; ++px16) {
        int px = px0 + wv * 32 + px16 * 16 + n;
        #pragma unroll
        for (int mt = 0; mt < 4; ++mt) {
            #pragma unroll
            for (int reg = 0; reg < 4; ++reg) {
                int co = co0 + mt * 16 + q * 4 + reg;
                if (co < Mreal) {
                    float v = acc[mt][px16][reg];
                    if (bias) v += bias[co];
                    if (act == 1) v = fmaxf(v, 0.f);
                    size_t o = ((size_t)b * Mreal + co) * Nn + px;
                    if (res)  v += res[o];
                    if (outf) outf[o] = v;
                    if (outh) outh[o] = f2bf(v);
                }
            }
        }
    }
}

// ---------------------------------------------------------------------------
// Vectorized f32 1x1 conv (tier-2 only).
// ---------------------------------------------------------------------------
template <int TCO>
__global__ __launch_bounds__(256) void conv1x1v_kernel(const float* __restrict__ in,
                                                       const float* __restrict__ wgt,
                                                       int wstride,
                                                       const float* __restrict__ bias,
                                                       const float* __restrict__ res,
                                                       float* __restrict__ out,
                                                       int Cin, int Cout, int act) {
    int pg  = blockIdx.x * 256 + threadIdx.x;
    int b   = blockIdx.z;
    int co0 = blockIdx.y * TCO;

    const float* wrow[TCO];
    #pragma unroll
    for (int i = 0; i < TCO; ++i) {
        int co = co0 + i; if (co > Cout - 1) co = Cout - 1;
        wrow[i] = wgt + (size_t)co * wstride;
    }

    float4 acc[TCO];
    #pragma unroll
    for (int i = 0; i < TCO; ++i) acc[i] = make_float4(0.f, 0.f, 0.f, 0.f);

    const float* ib = in + (size_t)b * Cin * Nn + (size_t)pg * 4;
    #pragma unroll 8
    for (int ci = 0; ci < Cin; ++ci) {
        float4 v = *(const float4*)(ib + (size_t)ci * Nn);
        #pragma unroll
        for (int i = 0; i < TCO; ++i) {
            float w = wrow[i][ci];
            acc[i].x += v.x * w; acc[i].y += v.y * w;
            acc[i].z += v.z * w; acc[i].w += v.w * w;
        }
    }

    #pragma unroll
    for (int i = 0; i < TCO; ++i) {
        int co = co0 + i;
        if (co < Cout) {
            float4 r = acc[i];
            if (bias) { float bb = bias[co]; r.x += bb; r.y += bb; r.z += bb; r.w += bb; }
            if (act == 1) {
                r.x = fmaxf(r.x, 0.f); r.y = fmaxf(r.y, 0.f);
                r.z = fmaxf(r.z, 0.f); r.w = fmaxf(r.w, 0.f);
            }
            size_t o = ((size_t)b * Cout + co) * Nn + (size_t)pg * 4;
            if (res) {
                float4 rv = *(const float4*)(res + o);
                r.x += rv.x; r.y += rv.y; r.z += rv.z; r.w += rv.w;
            }
            *(float4*)(out + o) = r;
        }
    }
}

// ---------------------------------------------------------------------------
// Depthwise 3x3 f32 (tier-2).
// ---------------------------------------------------------------------------
__global__ __launch_bounds__(256) void dw3x3_kernel(const float* __restrict__ in,
                                                    const float* __restrict__ w,
                                                    float* __restrict__ out, int Ct) {
    int p = blockIdx.x * 256 + threadIdx.x;
    int c = blockIdx.y;
    int b = blockIdx.z;
    int y = p >> 7, x = p & (Wb - 1);
    const float* ib = in + ((size_t)b * Ct + c) * Nn;
    float wl[9];
    #pragma unroll
    for (int k = 0; k < 9; ++k) wl[k] = w[c * 9 + k];
    float acc = 0.f;
    #pragma unroll
    for (int dy = 0; dy < 3; ++dy) {
        int yy = y + dy - 1;
        if (yy < 0 || yy >= Hh) continue;
        #pragma unroll
        for (int dx = 0; dx < 3; ++dx) {
            int xx = x + dx - 1;
            if (xx < 0 || xx >= Wb) continue;
            acc += wl[dy * 3 + dx] * ib[yy * Wb + xx];
        }
    }
    out[((size_t)b * Ct + c) * Nn + p] = acc;
}

// ---------------------------------------------------------------------------
// Depthwise 3x3 bf16-in/f32-out v2: LDS-tiled, vectorized, barrier-free ssq.
// grid: (Hh/16, Ct, Bt), block 256.
// Index map (ts col = gx+8): output gx = x0+p, tap dx -> ts col x0+p+dx+7.
// Row base &ts[..][x0+4] -> e[j], j = p+dx+3 (e[p+3..p+5], j in 3..12).
// ---------------------------------------------------------------------------
__global__ __launch_bounds__(256) void dw3x3_bf16_v2_kernel(const ushort_t* __restrict__ in,
                                                            const float* __restrict__ w,
                                                            float* __restrict__ out, int Ct,
                                                            float* __restrict__ ssq,
                                                            int nrmC) {
    const int gy0 = blockIdx.x * 16;
    const int c   = blockIdx.y;
    const int b   = blockIdx.z;
    const int tid = threadIdx.x;

    __shared__ float ts[20][144];

    const ushort_t* ib = in + ((size_t)b * Ct + c) * Nn;
    iel6_stage(ts, ib, gy0, tid);
    __syncthreads();

    float wl[9];
    #pragma unroll
    for (int k = 0; k < 9; ++k) wl[k] = w[c * 9 + k];

    const int r = tid >> 4;
    const int s = tid & 15;
    int x0 = 8 * s;
    float a[8] = {0.f, 0.f, 0.f, 0.f, 0.f, 0.f, 0.f, 0.f};
    #pragma unroll
    for (int dy = 0; dy < 3; ++dy) {
        const float* row = &ts[r + 1 + dy][x0 + 4];
        float4 e0 = *(const float4*)row;
        float4 e1 = *(const float4*)(row + 4);
        float4 e2 = *(const float4*)(row + 8);
        float4 e3 = *(const float4*)(row + 12);
        float e[16] = {e0.x, e0.y, e0.z, e0.w, e1.x, e1.y, e1.z, e1.w,
                       e2.x, e2.y, e2.z, e2.w, e3.x, e3.y, e3.z, e3.w};
        float w0 = wl[dy * 3], w1 = wl[dy * 3 + 1], w2 = wl[dy * 3 + 2];
        #pragma unroll
        for (int p = 0; p < 8; ++p)
            a[p] += w0 * e[p + 3] + w1 * e[p + 4] + w2 * e[p + 5];
    }
    float* ob = out + ((size_t)b * Ct + c) * Nn + (gy0 + r) * Wb + x0;
    float4 s0; s0.x = a[0]; s0.y = a[1]; s0.z = a[2]; s0.w = a[3];
    float4 s1; s1.x = a[4]; s1.y = a[5]; s1.z = a[6]; s1.w = a[7];
    *(float4*)ob       = s0;
    *(float4*)(ob + 4) = s1;

    if (ssq != nullptr && c < nrmC) {
        float s2sum = 0.f;
        #pragma unroll
        for (int p = 0; p < 8; ++p) s2sum += a[p] * a[p];
        #pragma unroll
        for (int o = 32; o > 0; o >>= 1) s2sum += __shfl_xor(s2sum, o, 64);
        if ((tid & 63) == 0) atomicAdd(&ssq[(size_t)b * nrmC + c], s2sum);
    }
}

// ---------------------------------------------------------------------------
// L2 normalize along N (in-place, tier-2). grid: (Cc, 1, Bt).
// ---------------------------------------------------------------------------
__global__ __launch_bounds__(256) void l2norm_kernel(float* __restrict__ data, int cstride) {
    int b = blockIdx.z, c = blockIdx.x;
    float* ptr = data + ((size_t)b * cstride + c) * Nn;
    int t = threadIdx.x;
    float s = 0.f;
    for (int i = t; i < Nn; i += 256) { float v = ptr[i]; s += v * v; }
    __shared__ float red[256];
    red[t] = s; __syncthreads();
    for (int st = 128; st > 0; st >>= 1) { if (t < st) red[t] += red[t + st]; __syncthreads(); }
    float scale = 1.0f / fmaxf(sqrtf(red[0]), 1e-12f);
    for (int i = t; i < Nn; i += 256) ptr[i] *= scale;
}

// ---------------------------------------------------------------------------
// Gate stage 2 + final.
// ---------------------------------------------------------------------------
__global__ __launch_bounds__(256) void gate2_kernel(const float* __restrict__ gmid,
                                                    const float* __restrict__ w2,
                                                    const float* __restrict__ b2,
                                                    float* __restrict__ blocksums,
                                                    int out_off) {
    int p = blockIdx.x * 256 + threadIdx.x;
    int b = blockIdx.z;
    float acc = b2[0];
    const float* ib = gmid + (size_t)b * 64 * Nn + p;
    #pragma unroll 8
    for (int ci = 0; ci < 64; ++ci) acc += ib[(size_t)ci * Nn] * w2[ci];
    float g = 1.0f / (1.0f + expf(-acc));
    __shared__ float red[256];
    int t = threadIdx.x;
    red[t] = g; __syncthreads();
    for (int st = 128; st > 0; st >>= 1) { if (t < st) red[t] += red[t + st]; __syncthreads(); }
    if (t == 0) blocksums[out_off + b * 64 + blockIdx.x] = red[0];
}

__global__ void gate_final_kernel(const float* __restrict__ blocksums,
                                  int* __restrict__ dk_out) {
    __shared__ double sred[256];
    int t = threadIdx.x;
    sred[t] = (double)blocksums[t];
    __syncthreads();
    for (int st = 128; st > 0; st >>= 1) { if (t < st) sred[t] += sred[t + st]; __syncthreads(); }
    if (t == 0) {
        double mean = sred[0] / (double)(Bn * Nn);
        float val = 16.0f * (float)mean;
        int dk = (int)val;
        if (dk < 1) dk = 1;
        if (dk > 16) dk = 16;
        *dk_out = dk;
    }
}

// ---------------------------------------------------------------------------
// QK^T partial (f32). grid: (NS, HEADS, Bt).
// ---------------------------------------------------------------------------
__global__ __launch_bounds__(256) void attn_qk_partial_kernel(const float* __restrict__ q,
                                                              const float* __restrict__ k,
                                                              int kstride,
                                                              float* __restrict__ partial) {
    int ns = blockIdx.x, h = blockIdx.y, b = blockIdx.z;
    int t = threadIdx.x;
    int c = t >> 4, d = t & 15;
    __shared__ float qs[16][65];
    __shared__ float ks[16][65];
    const float* qb = q + ((size_t)b * Cc + h * CHh) * Nn;
    const float* kb = k + ((size_t)b * kstride + h * CHh) * Nn;
    float acc = 0.f;
    int nbeg = ns * (Nn / NS);
    for (int n0 = nbeg; n0 < nbeg + (Nn / NS); n0 += 64) {
        for (int idx = t; idx < 1024; idx += 256) {
            int r = idx >> 6, col = idx & 63;
            qs[r][col] = qb[(size_t)r * Nn + n0 + col];
            ks[r][col] = kb[(size_t)r * Nn + n0 + col];
        }
        __syncthreads();
        #pragma unroll
        for (int j = 0; j < 64; ++j) acc += qs[c][j] * ks[d][j];
        __syncthreads();
    }
    partial[(((size_t)(b * HEADS + h)) * NS + ns) * 256 + t] = acc;
}

// reduce + temperature + (optional) fused L2-norm scaling.
__global__ __launch_bounds__(256) void attn_reduce_kernel(const float* __restrict__ partial,
                                                          const float* __restrict__ temp,
                                                          const float* __restrict__ qss,
                                                          const float* __restrict__ kss,
                                                          float* __restrict__ attnp) {
    int bh = blockIdx.x;
    int h = bh % HEADS;
    int t = threadIdx.x;
    const float* pp = partial + (size_t)bh * NS * 256 + t;
    float s = 0.f;
    #pragma unroll 8
    for (int ns = 0; ns < NS; ++ns) s += pp[(size_t)ns * 256];
    float scale = temp[h];
    if (qss != nullptr) {
        int b  = bh / HEADS;
        int cQ = h * CHh + (t >> 4);
        int cK = h * CHh + (t & 15);
        float nq = fmaxf(sqrtf(qss[(size_t)b * Cc + cQ]), 1e-12f);
        float nk = fmaxf(sqrtf(kss[(size_t)b * Cc + cK]), 1e-12f);
        scale = scale / (nq * nk);
    }
    attnp[(size_t)bh * 256 + t] = s * scale;
}

__global__ void topk_softmax_kernel(float* __restrict__ attnp, const int* __restrict__ dkp) {
    int bh = blockIdx.x;
    int c = threadIdx.x;
    if (c >= 16) return;
    float* row = attnp + ((size_t)bh * CHh + c) * CHh;
    float a[16];
    #pragma unroll
    for (int d = 0; d < 16; ++d) a[d] = row[d];
    int dk = *dkp;
    unsigned keep = 0;
    float m = -INFINITY;
    #pragma unroll
    for (int d = 0; d < 16; ++d) {
        int rank = 0;
        #pragma unroll
        for (int j = 0; j < 16; ++j)
            rank += (a[j] > a[d]) || (a[j] == a[d] && j < d);
        if (rank < dk) { keep |= (1u << d); m = fmaxf(m, a[d]); }
    }
    float e[16]; float s = 0.f;
    #pragma unroll
    for (int d = 0; d < 16; ++d) {
        e[d] = (keep >> d & 1u) ? expf(a[d] - m) : 0.f;
        s += e[d];
    }
    float invs = 1.0f / s;
    #pragma unroll
    for (int d = 0; d < 16; ++d) row[d] = e[d] * invs;
}

// attn_v: f32 out (tier-2)
__global__ __launch_bounds__(256) void attn_v_kernel(const float* __restrict__ attnp,
                                                     const float* __restrict__ v,
                                                     float* __restrict__ out) {
    int p = blockIdx.x * 256 + threadIdx.x;
    int cg = blockIdx.y;
    int b = blockIdx.z;
    int h = cg >> 4, cr = cg & 15;
    const float* arow = attnp + (((size_t)b * HEADS + h) * CHh + cr) * CHh;
    const float* vb = v + ((size_t)b * Cc + h * CHh) * Nn + p;
    float acc = 0.f;
    #pragma unroll
    for (int d = 0; d < 16; ++d) acc += arow[d] * vb[(size_t)d * Nn];
    out[((size_t)b * Cc + cg) * Nn + p] = acc;
}

// attn_v: bf16 out.
__global__ __launch_bounds__(256) void attn_v_bf16_kernel(const float* __restrict__ attnp,
                                                          const float* __restrict__ v,
                                                          int vstride, int voff,
                                                          ushort_t* __restrict__ out) {
    int p = blockIdx.x * 256 + threadIdx.x;
    int cg = blockIdx.y;
    int b = blockIdx.z;
    int h = cg >> 4, cr = cg & 15;
    const float* arow = attnp + (((size_t)b * HEADS + h) * CHh + cr) * CHh;
    const float* vb = v + ((size_t)b * vstride + voff + h * CHh) * Nn + p;
    float acc = 0.f;
    #pragma unroll
    for (int d = 0; d < 16; ++d) acc += arow[d] * vb[(size_t)d * Nn];
    out[((size_t)b * Cc + cg) * Nn + p] = f2bf(acc);
}

// ---------------------------------------------------------------------------
// Fused IEL tail v6: shared-u two-stage (exact padding), all-aligned LDS,
// fast tanh, stage(t2) overlapped with outer(t1).
//   u  = conv3x3(t, dw)         (shared intermediate, in LDS)
//   s  = conv3x3(u, dw1/dw2)
//   out = (tanh(s1)+u1) * (tanh(s2)+u2)
// LDS 21.9 KB -> 7 blocks/CU. grid: (Hh/16, HID, Bt), block 256.
// ---------------------------------------------------------------------------
__global__ __launch_bounds__(256) void iel_tail_v6_kernel(const ushort_t* __restrict__ Th,
                                                          const float* __restrict__ dww,
                                                          const float* __restrict__ dw1p,
                                                          const float* __restrict__ dw2p,
                                                          ushort_t* __restrict__ PRh) {
    const int gy0 = blockIdx.x * 16;
    const int c   = blockIdx.y;
    const int b   = blockIdx.z;
    const int tid = threadIdx.x;
    const int r   = tid >> 4;
    const int s   = tid & 15;

    __shared__ float ts[20][144];   // 11520 B
    __shared__ float us[18][144];   // 10368 B

    const ushort_t* t1 = Th + ((size_t)b * HID2 + c) * Nn;
    const ushort_t* t2 = Th + ((size_t)b * HID2 + HID + c) * Nn;
    ushort_t* outp = PRh + ((size_t)b * HID + c) * Nn;

    // phase 1: stage t1
    iel6_stage(ts, t1, gy0, tid);
    __syncthreads();
    // phase 2: u1 = conv(t1, dwA)
    iel6_ustage(ts, us, dww + (size_t)c * 9, gy0, tid);
    __syncthreads();
    // phase 3: stage t2 (writes ts) overlapped with outer1 (reads us)
    iel6_stage(ts, t2, gy0, tid);
    float keep[8];
    iel6_outer(us, dw1p + (size_t)c * 9, r, s, keep);
    __syncthreads();
    // phase 4: u2 = conv(t2, dwB)
    iel6_ustage(ts, us, dww + (size_t)(HID + c) * 9, gy0, tid);
    __syncthreads();
    // phase 5: outer2 + multiply + store
    float res[8];
    iel6_outer(us, dw2p + (size_t)c * 9, r, s, res);
    uint4 pk;
    pk.x = (unsigned)f2bf(keep[0] * res[0]) | ((unsigned)f2bf(keep[1] * res[1]) << 16);
    pk.y = (unsigned)f2bf(keep[2] * res[2]) | ((unsigned)f2bf(keep[3] * res[3]) << 16);
    pk.z = (unsigned)f2bf(keep[4] * res[4]) | ((unsigned)f2bf(keep[5] * res[5]) << 16);
    pk.w = (unsigned)f2bf(keep[6] * res[6]) | ((unsigned)f2bf(keep[7] * res[7]) << 16);
    *(uint4*)(outp + (gy0 + r) * Wb + s * 8) = pk;
}

// f32 IEL tail (tier-2 fallback; per-chunk layout).
__global__ __launch_bounds__(256) void iel_tail_f32_kernel(const float* __restrict__ t1p,
                                                           const float* __restrict__ t2p,
                                                           const float* __restrict__ dwA,
                                                           const float* __restrict__ dwB,
                                                           const float* __restrict__ dw1p,
                                                           const float* __restrict__ dw2p,
                                                           float* __restrict__ prod) {
    const int c = blockIdx.y;
    const int tilesx = Wb / 16;
    const int ty0 = (blockIdx.x / tilesx) * 16;
    const int tx0 = (blockIdx.x % tilesx) * 16;
    const int tid = threadIdx.x;

    __shared__ float ts[2][20][24];
    __shared__ float us[2][18][24];

    const float* t1 = t1p + (size_t)c * Nn;
    const float* t2 = t2p + (size_t)c * Nn;

    for (int idx = tid; idx < 400; idx += 256) {
        int i = idx / 20, j = idx % 20;
        int gy = ty0 - 2 + i, gx = tx0 - 2 + j;
        bool ok = (gy >= 0 && gy < Hh && gx >= 0 && gx < Wb);
        ts[0][i][j] = ok ? t1[gy * Wb + gx] : 0.f;
        ts[1][i][j] = ok ? t2[gy * Wb + gx] : 0.f;
    }
    __syncthreads();

    float wA[9], wB[9], w1[9], w2[9];
    #pragma unroll
    for (int k = 0; k < 9; ++k) {
        wA[k] = dwA[c * 9 + k];
        wB[k] = dwB[c * 9 + k];
        w1[k] = dw1p[c * 9 + k];
        w2[k] = dw2p[c * 9 + k];
    }

    for (int idx = tid; idx < 324; idx += 256) {
        int i = idx / 18, j = idx % 18;
        int gy = ty0 - 1 + i, gx = tx0 - 1 + j;
        float a0 = 0.f, a1 = 0.f;
        if (gy >= 0 && gy < Hh && gx >= 0 && gx < Wb) {
            #pragma unroll
            for (int dy = 0; dy < 3; ++dy)
                #pragma unroll
                for (int dx = 0; dx < 3; ++dx) {
                    a0 += wA[dy * 3 + dx] * ts[0][i + dy][j + dx];
                    a1 += wB[dy * 3 + dx] * ts[1][i + dy][j + dx];
                }
        }
        us[0][i][j] = a0;
        us[1][i][j] = a1;
    }
    __syncthreads();

    int ty = tid >> 4, tx = tid & 15;
    float c1 = us[0][ty + 1][tx + 1];
    float c2 = us[1][ty + 1][tx + 1];
    float s1 = 0.f, s2 = 0.f;
    #pragma unroll
    for (int dy = 0; dy < 3; ++dy)
        #pragma unroll
        for (int dx = 0; dx < 3; ++dx) {
            s1 += w1[dy * 3 + dx] * us[0][ty + dy][tx + dx];
            s2 += w2[dy * 3 + dx] * us[1][ty + dy][tx + dx];
        }
    float x1t = tanhf(s1) + c1;
    float x2t = tanhf(s2) + c2;
    prod[(size_t)c * Nn + (ty0 + ty) * Wb + (tx0 + tx)] = x1t * x2t;
}

// ---------------------------------------------------------------------------
// Host launcher
// ---------------------------------------------------------------------------
extern "C" void kernel_launch(void* const* d_in, const int* in_sizes, int n_in,
                              void* d_out, int out_size, void* d_ws, size_t ws_size,
                              hipStream_t stream) {
    const float* x      = (const float*)d_in[0];
    const float* y      = (const float*)d_in[1];
    const float* ln_w   = (const float*)d_in[2];
    const float* ln_b   = (const float*)d_in[3];
    const float* temp   = (const float*)d_in[4];
    const float* q_w    = (const float*)d_in[5];
    const float* qdw_w  = (const float*)d_in[6];
    const float* kv_w   = (const float*)d_in[7];
    const float* kvdw_w = (const float*)d_in[8];
    const float* po_w   = (const float*)d_in[9];
    const float* g1_w   = (const float*)d_in[10];
    const float* g1_b   = (const float*)d_in[11];
    const float* g2_w   = (const float*)d_in[12];
    const float* g2_b   = (const float*)d_in[13];
    const float* pin_w  = (const float*)d_in[14];
    const float* dw_w   = (const float*)d_in[15];
    const float* dw1_w  = (const float*)d_in[16];
    const float* dw2_w  = (const float*)d_in[17];
    const float* pout_w = (const float*)d_in[18];
    float* out = (float*)d_out;

    // smalls in first 1 MiB
    char* ws = (char*)d_ws;
    float* attn      = (float*)ws;                        // 32 KB
    float* blocksums = (float*)(ws + 32768);              // 1 KB
    int*   dk        = (int*)(ws + 33792);
    ushort_t* qWh  = (ushort_t*)(ws + 34816);             // 128x128
    ushort_t* kvWh = qWh + 16384;                         // 256x128
    ushort_t* poWh = kvWh + 32768;                        // 128x128
    ushort_t* g1Wh = poWh + 16384;                        // 64x128
    ushort_t* Wh1  = g1Wh + 8192;                         // 704x128
    ushort_t* Wh2  = Wh1 + (size_t)MPAD * Cc;             // 128x352
    float* qss = (float*)(ws + 458752);                   // [Bn][128] sumsq(q)
    float* kss = (float*)(ws + 460800);                   // [Bn][128] sumsq(k)
    float* pool    = (float*)(ws + (1u << 20));

    const size_t CN    = (size_t)Cc * Nn;
    const size_t SLOT1 = (size_t)Bn * CN;
    const size_t TIER1_NEED = 65536 + 6 * SLOT1 * 4;

    dim3 blk(256);
    const int PGX = Nn / 1024;

    if (ws_size >= TIER1_NEED) {
        // ---- buffers ----
        float* S3 = pool;                                  // q2 f32 [B][128][Nn]
        float* S4 = pool + 8 * 1024 * 1024;                // k2+v2 f32 [B][256][Nn]
        ushort_t* XNh  = (ushort_t*)(pool + 24 * 1024 * 1024);
        ushort_t* YNh  = XNh + Bn * CN;
        ushort_t* KV1h = YNh + Bn * CN;
        ushort_t* Q1h  = KV1h + 2 * Bn * CN;
        float* gmid    = (float*)Q1h;
        float* partial = gmid;
        ushort_t* AOh  = XNh;

        wconv_pad_rows_kernel<<<dim3(64), blk, 0, stream>>>(q_w, qWh, 128, Cc);
        wconv_pad_rows_kernel<<<dim3(128), blk, 0, stream>>>(kv_w, kvWh, 256, Cc);
        wconv_pad_rows_kernel<<<dim3(64), blk, 0, stream>>>(po_w, poWh, 128, Cc);
        wconv_pad_rows_kernel<<<dim3(32), blk, 0, stream>>>(g1_w, g1Wh, 64, Cc);
        wconv_pad_rows_kernel<<<dim3(MPAD * Cc / 256), blk, 0, stream>>>(pin_w, Wh1, HID2, Cc);
        wconv_pad_cols_kernel<<<dim3(Cc * KPAD2 / 256), blk, 0, stream>>>(pout_w, Wh2, HID, KPAD2);
        zero_f32_kernel<<<dim3(4), blk, 0, stream>>>(qss, 2 * Bn * Cc);  // qss+kss contiguous

        // ---- Phase A ----
        ln_bf16_kernel<<<dim3(Nn / 256, 1, Bn), blk, 0, stream>>>(x, ln_w, ln_b, XNh);
        ln_bf16_kernel<<<dim3(Nn / 256, 1, Bn), blk, 0, stream>>>(y, ln_w, ln_b, YNh);

        gemm_bf16_kernel<<<dim3(Nn / 128, 2, Bn), blk, 0, stream>>>(
            XNh, qWh, nullptr, nullptr, nullptr, Q1h, Cc, Cc, Cc, 0);
        dw3x3_bf16_v2_kernel<<<dim3(Hh / 16, Cc, Bn), blk, 0, stream>>>(
            Q1h, qdw_w, S3, Cc, qss, Cc);

        gemm_bf16_kernel<<<dim3(Nn / 128, 4, Bn), blk, 0, stream>>>(
            YNh, kvWh, nullptr, nullptr, nullptr, KV1h, Cc, Cc, 2 * Cc, 0);
        dw3x3_bf16_v2_kernel<<<dim3(Hh / 16, 2 * Cc, Bn), blk, 0, stream>>>(
            KV1h, kvdw_w, S4, 2 * Cc, kss, Cc);

        gemm_bf16_kernel<<<dim3(Nn / 128, 1, Bn), blk, 0, stream>>>(
            XNh, g1Wh, g1_b, nullptr, gmid, nullptr, Cc, Cc, 64, 1);
        gate2_kernel<<<dim3(Nn / 256, 1, Bn), blk, 0, stream>>>(gmid, g2_w, g2_b, blocksums, 0);
        gate_final_kernel<<<dim3(1), blk, 0, stream>>>(blocksums, dk);

        // L2 norms folded into attn_reduce via qss/kss (no l2norm passes).
        attn_qk_partial_kernel<<<dim3(NS, HEADS, Bn), blk, 0, stream>>>(S3, S4, 2 * Cc, partial);
        attn_reduce_kernel<<<dim3(Bn * HEADS), blk, 0, stream>>>(partial, temp, qss, kss, attn);
        topk_softmax_kernel<<<dim3(Bn * HEADS), dim3(16), 0, stream>>>(attn, dk);
        attn_v_bf16_kernel<<<dim3(Nn / 256, Cc, Bn), blk, 0, stream>>>(
            attn, S4, 2 * Cc, Cc, AOh);

        gemm_bf16_kernel<<<dim3(Nn / 128, 2, Bn), blk, 0, stream>>>(
            AOh, poWh, nullptr, x, out, nullptr, Cc, Cc, Cc, 0);

        // ---- Phase B ----
        ushort_t* ZNh = (ushort_t*)pool;
        ushort_t* Th  = ZNh + Bn * CN;
        ushort_t* PRh = Th + (size_t)Bn * HID2 * Nn;

        ln_bf16_kernel<<<dim3(Nn / 256, 1, Bn), blk, 0, stream>>>(out, ln_w, ln_b, ZNh);

        gemm_bf16_kernel<<<dim3(Nn / 128, MPAD / 64, Bn), blk, 0, stream>>>(
            ZNh, Wh1, nullptr, nullptr, nullptr, Th, Cc, Cc, HID2, 0);

        iel_tail_v6_kernel<<<dim3(Hh / 16, HID, Bn), blk, 0, stream>>>(
            Th, dw_w, dw1_w, dw2_w, PRh);

        gemm_bf16_kernel<<<dim3(Nn / 128, 2, Bn), blk, 0, stream>>>(
            PRh, Wh2, nullptr, out, out, nullptr, HID, KPAD2, Cc, 0);
    } else {
        // ================= Tier 2: per-batch f32 fallback ===================
        float* s0 = pool;
        float* s1 = pool + 1 * CN;
        float* s2 = pool + 2 * CN;
        float* s3 = pool + 3 * CN;
        float* s4 = pool + 4 * CN;
        float* s5 = pool + 5 * CN;

        for (int b = 0; b < Bn; ++b) {
            const float* xb = x + (size_t)b * CN;
            ln_kernel<<<dim3(Nn / 256, 1, 1), blk, 0, stream>>>(xb, ln_w, ln_b, s0);
            conv1x1v_kernel<4><<<dim3(PGX, 16, 1), blk, 0, stream>>>(
                s0, g1_w, Cc, g1_b, nullptr, s1, Cc, 64, 1);
            gate2_kernel<<<dim3(Nn / 256, 1, 1), blk, 0, stream>>>(
                s1, g2_w, g2_b, blocksums, b * 64);
        }
        gate_final_kernel<<<dim3(1), blk, 0, stream>>>(blocksums, dk);

        for (int b = 0; b < Bn; ++b) {
            const float* xb = x + (size_t)b * CN;
            const float* yb = y + (size_t)b * CN;
            float* outb = out + (size_t)b * CN;
            float* attnb = attn + (size_t)b * HEADS * CHh * CHh;

            ln_kernel<<<dim3(Nn / 256, 1, 1), blk, 0, stream>>>(xb, ln_w, ln_b, s0);
            ln_kernel<<<dim3(Nn / 256, 1, 1), blk, 0, stream>>>(yb, ln_w, ln_b, s1);

            conv1x1v_kernel<8><<<dim3(PGX, 16, 1), blk, 0, stream>>>(
                s0, q_w, Cc, nullptr, nullptr, s2, Cc, Cc, 0);
            dw3x3_kernel<<<dim3(Nn / 256, Cc, 1), blk, 0, stream>>>(s2, qdw_w, s3, Cc);
            l2norm_kernel<<<dim3(Cc, 1, 1), blk, 0, stream>>>(s3, Cc);

            conv1x1v_kernel<8><<<dim3(PGX, 16, 1), blk, 0, stream>>>(
                s1, kv_w, Cc, nullptr, nullptr, s2, Cc, Cc, 0);
            dw3x3_kernel<<<dim3(Nn / 256, Cc, 1), blk, 0, stream>>>(s2, kvdw_w, s4, Cc);
            l2norm_kernel<<<dim3(Cc, 1, 1), blk, 0, stream>>>(s4, Cc);

            conv1x1v_kernel<8><<<dim3(PGX, 16, 1), blk, 0, stream>>>(
                s1, kv_w + 128 * 128, Cc, nullptr, nullptr, s2, Cc, Cc, 0);
            dw3x3_kernel<<<dim3(Nn / 256, Cc, 1), blk, 0, stream>>>(s2, kvdw_w + 128 * 9, s5, Cc);

            attn_qk_partial_kernel<<<dim3(NS, HEADS, 1), blk, 0, stream>>>(s3, s4, Cc, s2);
            attn_reduce_kernel<<<dim3(HEADS), blk, 0, stream>>>(s2, temp, nullptr, nullptr, attnb);
            topk_softmax_kernel<<<dim3(HEADS), dim3(16), 0, stream>>>(attnb, dk);
            attn_v_kernel<<<dim3(Nn / 256, Cc, 1), blk, 0, stream>>>(attnb, s5, s2);

            conv1x1v_kernel<8><<<dim3(PGX, 16, 1), blk, 0, stream>>>(
                s2, po_w, Cc, nullptr, xb, outb, Cc, Cc, 0);
        }

        const int CHUNK = 170;
        const size_t TCH = (size_t)CHUNK * Nn;
        float* zn   = pool;
        float* T1   = pool + CN;
        float* T2   = T1 + TCH;
        float* prod = T2 + TCH;
        for (int b = 0; b < Bn; ++b) {
            float* outb = out + (size_t)b * CN;
            ln_kernel<<<dim3(Nn / 256, 1, 1), blk, 0, stream>>>(outb, ln_w, ln_b, zn);
            for (int c0 = 0; c0 < HID; c0 += CHUNK) {
                conv1x1v_kernel<20><<<dim3(PGX, 9, 1), blk, 0, stream>>>(
                    zn, pin_w + (size_t)c0 * Cc, Cc, nullptr, nullptr, T1, Cc, CHUNK, 0);
                conv1x1v_kernel<20><<<dim3(PGX, 9, 1), blk, 0, stream>>>(
                    zn, pin_w + (size_t)(HID + c0) * Cc, Cc, nullptr, nullptr, T2, Cc, CHUNK, 0);
                iel_tail_f32_kernel<<<dim3(64, CHUNK, 1), blk, 0, stream>>>(
                    T1, T2, dw_w + c0 * 9, dw_w + (HID + c0) * 9,
                    dw1_w + c0 * 9, dw2_w + c0 * 9, prod);
                conv1x1v_kernel<8><<<dim3(PGX, 16, 1), blk, 0, stream>>>(
                    prod, pout_w + c0, HID, nullptr, outb, outb, CHUNK, Cc, 0);
            }
        }
    }
}

// Round 5
// 632.937 us; speedup vs baseline: 1.0452x; 1.0452x over previous
//
#include <hip/hip_runtime.h>
#include <math.h>

// Problem constants
static constexpr int Bn    = 4;
static constexpr int Cc    = 128;
static constexpr int Hh    = 128;
static constexpr int Wb    = 128;
static constexpr int Nn    = Hh * Wb;      // 16384
static constexpr int HEADS = 8;
static constexpr int CHh   = 16;
static constexpr int HID   = 340;
static constexpr int HID2  = 680;
static constexpr int NS    = 64;
static constexpr int MPAD  = 704;          // pin M padded (680 -> 44*16)
static constexpr int KPAD2 = 352;          // pout K padded (340 -> 11*32)

typedef unsigned short ushort_t;
typedef __attribute__((ext_vector_type(8))) short short8;
typedef __attribute__((ext_vector_type(4))) float f32x4;

__device__ __forceinline__ ushort_t f2bf(float f) {
    unsigned u = __float_as_uint(f);
    return (ushort_t)((u + 0x7FFFu + ((u >> 16) & 1u)) >> 16);   // RNE
}
__device__ __forceinline__ float bf2f(ushort_t h) {
    return __uint_as_float(((unsigned)h) << 16);
}

// fast tanh: tanh(x) = 1 - 2/(e^{2|x|}+1), sign-restored.
__device__ __forceinline__ float fast_tanh(float x) {
    float a = fabsf(x);
    a = fminf(a, 12.0f);
    float e = __expf(2.0f * a);
    float r = 1.0f - 2.0f * __builtin_amdgcn_rcpf(e + 1.0f);
    return x < 0.0f ? -r : r;
}

// ---------------------------------------------------------------------------
// IEL v7 LDS helpers. Conflict-free layouts (stride 136 floats = 544 B):
//   ts[20][136]: ts[i][c] = t(gy0-2+i, c-4), data c = 4..131, zeros at
//                c=0..3 and 132..135.
//   us[18][136]: us[i][j] = u(gy0-1+i, j-1), data j = 0..129 (zero-forced
//                for u-pixel outside [0,127]), j=130..131 zero.
// Every LDS op is an aligned float4 with LANE STRIDE = 16 B (consecutive
// lanes -> consecutive 16B blocks -> no bank conflicts). No b64 reads.
// ---------------------------------------------------------------------------
__device__ __forceinline__ void iel7_stage(float (*ts)[136], const ushort_t* __restrict__ tp,
                                           int gy0, int tid) {
    // 640 tasks: i = row 0..19, s = 4-px strip 0..31
    for (int idx = tid; idx < 640; idx += 256) {
        int i = idx >> 5;
        int s = idx & 31;
        int gy = gy0 - 2 + i;
        float4 v; v.x = 0.f; v.y = 0.f; v.z = 0.f; v.w = 0.f;
        if (gy >= 0 && gy < Hh) {
            uint2 u = *(const uint2*)(tp + gy * Wb + 4 * s);
            v.x = bf2f((ushort_t)(u.x & 0xFFFF)); v.y = bf2f((ushort_t)(u.x >> 16));
            v.z = bf2f((ushort_t)(u.y & 0xFFFF)); v.w = bf2f((ushort_t)(u.y >> 16));
        }
        *(float4*)&ts[i][4 + 4 * s] = v;
        if (s == 0) {
            float4 z; z.x = 0.f; z.y = 0.f; z.z = 0.f; z.w = 0.f;
            *(float4*)&ts[i][0] = z;
        }
        if (s == 31) {
            float4 z; z.x = 0.f; z.y = 0.f; z.z = 0.f; z.w = 0.f;
            *(float4*)&ts[i][132] = z;
        }
    }
}

// u = conv3x3(t, wa), zero-padded. 594 tasks: i = 0..17 (gy = gy0-1+i),
// s = 0..32. Outputs j = 4s..4s+3 (u-pixel gx = 4s+p-1, zero-forced outside
// [0,127]); writes aligned f4 at us[i][4s]. Reads ts[i+dy][4s..4s+7]
// (2 aligned b128). Tap: t(4s+p+dx-2) -> ts col 4s+p+dx+2 -> e[p+dx+2].
__device__ __forceinline__ void iel7_ustage(const float (*ts)[136], float (*us)[136],
                                            const float* __restrict__ wa9,
                                            int gy0, int tid) {
    float wa[9];
    #pragma unroll
    for (int k = 0; k < 9; ++k) wa[k] = wa9[k];
    for (int idx = tid; idx < 594; idx += 256) {
        int i = idx / 33;
        int s = idx - i * 33;
        int gy = gy0 - 1 + i;
        float a[4] = {0.f, 0.f, 0.f, 0.f};
        if (gy >= 0 && gy < Hh) {
            #pragma unroll
            for (int dy = 0; dy < 3; ++dy) {
                const float* row = &ts[i + dy][4 * s];
                float4 e0 = *(const float4*)row;
                float4 e1 = *(const float4*)(row + 4);
                float e[8] = {e0.x, e0.y, e0.z, e0.w, e1.x, e1.y, e1.z, e1.w};
                float w0 = wa[dy * 3], w1 = wa[dy * 3 + 1], w2 = wa[dy * 3 + 2];
                #pragma unroll
                for (int p = 0; p < 4; ++p)
                    a[p] += w0 * e[p + 2] + w1 * e[p + 3] + w2 * e[p + 4];
            }
            #pragma unroll
            for (int p = 0; p < 4; ++p) {
                int gx = 4 * s + p - 1;
                if (gx < 0 || gx > 127) a[p] = 0.f;
            }
        }
        float4 o; o.x = a[0]; o.y = a[1]; o.z = a[2]; o.w = a[3];
        *(float4*)&us[i][4 * s] = o;
    }
}

// outer conv3x3(u, wb) + center. Thread (r, s): output row gy0+r, px
// gx = 4s..4s+3. Reads us[r+dy][4s..4s+7] (2 aligned b128).
// Tap u(gx+dx-1) -> j = 4s+p+dx -> e[p+dx]; center u(gx) -> e[p+1] @ dy=1.
__device__ __forceinline__ void iel7_outer(const float (*us)[136],
                                           const float* __restrict__ wb9,
                                           int r, int s, float res[4]) {
    float wb[9];
    #pragma unroll
    for (int k = 0; k < 9; ++k) wb[k] = wb9[k];
    float aa[4] = {0.f, 0.f, 0.f, 0.f};
    float ctr[4];
    #pragma unroll
    for (int dy = 0; dy < 3; ++dy) {
        const float* row = &us[r + dy][4 * s];
        float4 e0 = *(const float4*)row;
        float4 e1 = *(const float4*)(row + 4);
        float e[8] = {e0.x, e0.y, e0.z, e0.w, e1.x, e1.y, e1.z, e1.w};
        float w0 = wb[dy * 3], w1 = wb[dy * 3 + 1], w2 = wb[dy * 3 + 2];
        #pragma unroll
        for (int p = 0; p < 4; ++p)
            aa[p] += w0 * e[p] + w1 * e[p + 1] + w2 * e[p + 2];
        if (dy == 1) {
            #pragma unroll
            for (int p = 0; p < 4; ++p) ctr[p] = e[p + 1];
        }
    }
    #pragma unroll
    for (int p = 0; p < 4; ++p) res[p] = fast_tanh(aa[p]) + ctr[p];
}

// ---------------------------------------------------------------------------
// LayerNorm over channel axis, f32 out (tier-2). grid: (Nn/256, 1, Bt).
// ---------------------------------------------------------------------------
__global__ __launch_bounds__(256) void ln_kernel(const float* __restrict__ in,
                                                 const float* __restrict__ w,
                                                 const float* __restrict__ bias,
                                                 float* __restrict__ out) {
    int p = blockIdx.x * 256 + threadIdx.x;
    int b = blockIdx.z;
    const float* ib = in + (size_t)b * Cc * Nn + p;
    float s = 0.f, s2 = 0.f;
    #pragma unroll 8
    for (int c = 0; c < Cc; ++c) {
        float v = ib[(size_t)c * Nn];
        s += v; s2 += v * v;
    }
    float mean = s * (1.0f / Cc);
    float var  = s2 * (1.0f / Cc) - mean * mean;
    float inv  = 1.0f / sqrtf(var + 1e-6f);
    float* ob = out + (size_t)b * Cc * Nn + p;
    #pragma unroll 8
    for (int c = 0; c < Cc; ++c) {
        float v = ib[(size_t)c * Nn];
        ob[(size_t)c * Nn] = w[c] * ((v - mean) * inv) + bias[c];
    }
}

// LayerNorm writing bf16 (feeds MFMA GEMMs).
__global__ __launch_bounds__(256) void ln_bf16_kernel(const float* __restrict__ in,
                                                      const float* __restrict__ w,
                                                      const float* __restrict__ bias,
                                                      ushort_t* __restrict__ out) {
    int p = blockIdx.x * 256 + threadIdx.x;
    int b = blockIdx.z;
    const float* ib = in + (size_t)b * Cc * Nn + p;
    float s = 0.f, s2 = 0.f;
    #pragma unroll 8
    for (int c = 0; c < Cc; ++c) {
        float v = ib[(size_t)c * Nn];
        s += v; s2 += v * v;
    }
    float mean = s * (1.0f / Cc);
    float var  = s2 * (1.0f / Cc) - mean * mean;
    float inv  = 1.0f / sqrtf(var + 1e-6f);
    ushort_t* ob = out + (size_t)b * Cc * Nn + p;
    #pragma unroll 8
    for (int c = 0; c < Cc; ++c) {
        float v = ib[(size_t)c * Nn];
        ob[(size_t)c * Nn] = f2bf(w[c] * ((v - mean) * inv) + bias[c]);
    }
}

// ---------------------------------------------------------------------------
// Weight conversion f32 -> bf16 (+ padding variants).
// ---------------------------------------------------------------------------
__global__ __launch_bounds__(256) void wconv_pad_rows_kernel(const float* __restrict__ w,
                                                             ushort_t* __restrict__ o,
                                                             int rows, int K) {
    int idx = blockIdx.x * 256 + threadIdx.x;
    int r = idx / K, k = idx - r * K;
    o[idx] = (r < rows) ? f2bf(w[(size_t)r * K + k]) : (ushort_t)0;
}
__global__ __launch_bounds__(256) void wconv_pad_cols_kernel(const float* __restrict__ w,
                                                             ushort_t* __restrict__ o,
                                                             int K, int Kp) {
    int idx = blockIdx.x * 256 + threadIdx.x;
    int r = idx / Kp, k = idx - r * Kp;
    o[idx] = (k < K) ? f2bf(w[(size_t)r * K + k]) : (ushort_t)0;
}

// Zero a small f32 buffer (for ssq atomics).
__global__ __launch_bounds__(256) void zero_f32_kernel(float* __restrict__ p, int n) {
    int i = blockIdx.x * 256 + threadIdx.x;
    if (i < n) p[i] = 0.f;
}

// ---------------------------------------------------------------------------
// bf16 MFMA GEMM v2: out[b,co,p] = sum_ci W[co,ci] * Z[b,ci,p]
// ---------------------------------------------------------------------------
__global__ __launch_bounds__(256) void gemm_bf16_kernel(const ushort_t* __restrict__ Zh,
                                                        const ushort_t* __restrict__ Wh,
                                                        const float* __restrict__ bias,
                                                        const float* __restrict__ res,
                                                        float* outf,
                                                        ushort_t* outh,
                                                        int Cin, int Kpad, int Mreal,
                                                        int act) {
    const int b    = blockIdx.z;
    const int px0  = blockIdx.x * 128;
    const int co0  = blockIdx.y * 64;
    const int tid  = threadIdx.x;
    const int wv   = tid >> 6;
    const int lane = tid & 63;
    const int n    = lane & 15;
    const int q    = lane >> 4;

    __shared__ ushort_t Bl[128][40];

    const ushort_t* Zb = Zh + (size_t)b * Cin * Nn;

    f32x4 acc[4][2];
    #pragma unroll
    for (int i = 0; i < 4; ++i)
        #pragma unroll
        for (int j = 0; j < 2; ++j) acc[i][j] = (f32x4){0.f, 0.f, 0.f, 0.f};

    for (int k0 = 0; k0 < Kpad; k0 += 32) {
        {
            int r = tid >> 3;        // k row 0..31
            int s = tid & 7;         // 16-px chunk
            int ci = k0 + r;
            ushort_t tmp[16];
            if (ci < Cin) {
                const ushort_t* src = Zb + (size_t)ci * Nn + px0 + s * 16;
                uint4 v0 = *(const uint4*)src;
                uint4 v1 = *(const uint4*)(src + 8);
                tmp[0]  = (ushort_t)(v0.x & 0xFFFF); tmp[1]  = (ushort_t)(v0.x >> 16);
                tmp[2]  = (ushort_t)(v0.y & 0xFFFF); tmp[3]  = (ushort_t)(v0.y >> 16);
                tmp[4]  = (ushort_t)(v0.z & 0xFFFF); tmp[5]  = (ushort_t)(v0.z >> 16);
                tmp[6]  = (ushort_t)(v0.w & 0xFFFF); tmp[7]  = (ushort_t)(v0.w >> 16);
                tmp[8]  = (ushort_t)(v1.x & 0xFFFF); tmp[9]  = (ushort_t)(v1.x >> 16);
                tmp[10] = (ushort_t)(v1.y & 0xFFFF); tmp[11] = (ushort_t)(v1.y >> 16);
                tmp[12] = (ushort_t)(v1.z & 0xFFFF); tmp[13] = (ushort_t)(v1.z >> 16);
                tmp[14] = (ushort_t)(v1.w & 0xFFFF); tmp[15] = (ushort_t)(v1.w >> 16);
            } else {
                #pragma unroll
                for (int i = 0; i < 16; ++i) tmp[i] = 0;
            }
            #pragma unroll
            for (int i = 0; i < 16; ++i) Bl[s * 16 + i][r] = tmp[i];
        }
        __syncthreads();

        short8 bfrag[2];
        #pragma unroll
        for (int px16 = 0; px16 < 2; ++px16)
            bfrag[px16] = *(const short8*)&Bl[wv * 32 + px16 * 16 + n][q * 8];
        #pragma unroll
        for (int mt = 0; mt < 4; ++mt) {
            const ushort_t* wp = Wh + (size_t)(co0 + mt * 16 + n) * Kpad + k0 + q * 8;
            short8 afrag = *(const short8*)wp;
            #pragma unroll
            for (int px16 = 0; px16 < 2; ++px16)
                acc[mt][px16] = __builtin_amdgcn_mfma_f32_16x16x32_bf16(
                    afrag, bfrag[px16], acc[mt][px16], 0, 0, 0);
        }
        __syncthreads();
    }

    #pragma unroll
    for (int px16 = 0; px16 < 2; ++px16) {
        int px = px0 + wv * 32 + px16 * 16 + n;
        #pragma unroll
        for (int mt = 0; mt < 4; ++mt) {
            #pragma unroll
            for (int reg = 0; reg < 4; ++reg) {
                int co = co0 + mt * 16 + q * 4 + reg;
                if (co < Mreal) {
                    float v = acc[mt][px16][reg];
                    if (bias) v += bias[co];
                    if (act == 1) v = fmaxf(v, 0.f);
                    size_t o = ((size_t)b * Mreal + co) * Nn + px;
                    if (res)  v += res[o];
                    if (outf) outf[o] = v;
                    if (outh) outh[o] = f2bf(v);
                }
            }
        }
    }
}

// ---------------------------------------------------------------------------
// Vectorized f32 1x1 conv (tier-2 only).
// ---------------------------------------------------------------------------
template <int TCO>
__global__ __launch_bounds__(256) void conv1x1v_kernel(const float* __restrict__ in,
                                                       const float* __restrict__ wgt,
                                                       int wstride,
                                                       const float* __restrict__ bias,
                                                       const float* __restrict__ res,
                                                       float* __restrict__ out,
                                                       int Cin, int Cout, int act) {
    int pg  = blockIdx.x * 256 + threadIdx.x;
    int b   = blockIdx.z;
    int co0 = blockIdx.y * TCO;

    const float* wrow[TCO];
    #pragma unroll
    for (int i = 0; i < TCO; ++i) {
        int co = co0 + i; if (co > Cout - 1) co = Cout - 1;
        wrow[i] = wgt + (size_t)co * wstride;
    }

    float4 acc[TCO];
    #pragma unroll
    for (int i = 0; i < TCO; ++i) acc[i] = make_float4(0.f, 0.f, 0.f, 0.f);

    const float* ib = in + (size_t)b * Cin * Nn + (size_t)pg * 4;
    #pragma unroll 8
    for (int ci = 0; ci < Cin; ++ci) {
        float4 v = *(const float4*)(ib + (size_t)ci * Nn);
        #pragma unroll
        for (int i = 0; i < TCO; ++i) {
            float w = wrow[i][ci];
            acc[i].x += v.x * w; acc[i].y += v.y * w;
            acc[i].z += v.z * w; acc[i].w += v.w * w;
        }
    }

    #pragma unroll
    for (int i = 0; i < TCO; ++i) {
        int co = co0 + i;
        if (co < Cout) {
            float4 r = acc[i];
            if (bias) { float bb = bias[co]; r.x += bb; r.y += bb; r.z += bb; r.w += bb; }
            if (act == 1) {
                r.x = fmaxf(r.x, 0.f); r.y = fmaxf(r.y, 0.f);
                r.z = fmaxf(r.z, 0.f); r.w = fmaxf(r.w, 0.f);
            }
            size_t o = ((size_t)b * Cout + co) * Nn + (size_t)pg * 4;
            if (res) {
                float4 rv = *(const float4*)(res + o);
                r.x += rv.x; r.y += rv.y; r.z += rv.z; r.w += rv.w;
            }
            *(float4*)(out + o) = r;
        }
    }
}

// ---------------------------------------------------------------------------
// Depthwise 3x3 f32 (tier-2).
// ---------------------------------------------------------------------------
__global__ __launch_bounds__(256) void dw3x3_kernel(const float* __restrict__ in,
                                                    const float* __restrict__ w,
                                                    float* __restrict__ out, int Ct) {
    int p = blockIdx.x * 256 + threadIdx.x;
    int c = blockIdx.y;
    int b = blockIdx.z;
    int y = p >> 7, x = p & (Wb - 1);
    const float* ib = in + ((size_t)b * Ct + c) * Nn;
    float wl[9];
    #pragma unroll
    for (int k = 0; k < 9; ++k) wl[k] = w[c * 9 + k];
    float acc = 0.f;
    #pragma unroll
    for (int dy = 0; dy < 3; ++dy) {
        int yy = y + dy - 1;
        if (yy < 0 || yy >= Hh) continue;
        #pragma unroll
        for (int dx = 0; dx < 3; ++dx) {
            int xx = x + dx - 1;
            if (xx < 0 || xx >= Wb) continue;
            acc += wl[dy * 3 + dx] * ib[yy * Wb + xx];
        }
    }
    out[((size_t)b * Ct + c) * Nn + p] = acc;
}

// ---------------------------------------------------------------------------
// Depthwise 3x3 bf16-in/f32-out v3: conflict-free 4-px-per-lane LDS pattern.
// Thread (r,s): output row gy0+r, px gx = 4s..4s+3. Reads ts[r+1+dy][4s..4s+11]
// (3 aligned b128). Tap t(4s+p+dx-1) -> ts col 4s+p+dx+3 -> e[p+dx+3].
// grid: (Hh/16, Ct, Bt), block 256. LDS 10880 B. Barrier-free ssq.
// ---------------------------------------------------------------------------
__global__ __launch_bounds__(256) void dw3x3_bf16_v3_kernel(const ushort_t* __restrict__ in,
                                                            const float* __restrict__ w,
                                                            float* __restrict__ out, int Ct,
                                                            float* __restrict__ ssq,
                                                            int nrmC) {
    const int gy0 = blockIdx.x * 16;
    const int c   = blockIdx.y;
    const int b   = blockIdx.z;
    const int tid = threadIdx.x;

    __shared__ float ts[20][136];

    const ushort_t* ib = in + ((size_t)b * Ct + c) * Nn;
    iel7_stage(ts, ib, gy0, tid);
    __syncthreads();

    float wl[9];
    #pragma unroll
    for (int k = 0; k < 9; ++k) wl[k] = w[c * 9 + k];

    float* ob = out + ((size_t)b * Ct + c) * Nn;
    float s2sum = 0.f;
    #pragma unroll
    for (int it = 0; it < 2; ++it) {
        int idx = tid + it * 256;
        int r = idx >> 5;            // 0..15
        int s = idx & 31;            // 4-px strip
        float a[4] = {0.f, 0.f, 0.f, 0.f};
        #pragma unroll
        for (int dy = 0; dy < 3; ++dy) {
            const float* row = &ts[r + 1 + dy][4 * s];
            float4 e0 = *(const float4*)row;
            float4 e1 = *(const float4*)(row + 4);
            float4 e2 = *(const float4*)(row + 8);
            float e[12] = {e0.x, e0.y, e0.z, e0.w, e1.x, e1.y, e1.z, e1.w,
                           e2.x, e2.y, e2.z, e2.w};
            float w0 = wl[dy * 3], w1 = wl[dy * 3 + 1], w2 = wl[dy * 3 + 2];
            #pragma unroll
            for (int p = 0; p < 4; ++p)
                a[p] += w0 * e[p + 3] + w1 * e[p + 4] + w2 * e[p + 5];
        }
        float4 st; st.x = a[0]; st.y = a[1]; st.z = a[2]; st.w = a[3];
        *(float4*)(ob + (gy0 + r) * Wb + 4 * s) = st;
        s2sum += a[0] * a[0] + a[1] * a[1] + a[2] * a[2] + a[3] * a[3];
    }

    if (ssq != nullptr && c < nrmC) {
        #pragma unroll
        for (int o = 32; o > 0; o >>= 1) s2sum += __shfl_xor(s2sum, o, 64);
        if ((tid & 63) == 0) atomicAdd(&ssq[(size_t)b * nrmC + c], s2sum);
    }
}

// ---------------------------------------------------------------------------
// L2 normalize along N (in-place, tier-2). grid: (Cc, 1, Bt).
// ---------------------------------------------------------------------------
__global__ __launch_bounds__(256) void l2norm_kernel(float* __restrict__ data, int cstride) {
    int b = blockIdx.z, c = blockIdx.x;
    float* ptr = data + ((size_t)b * cstride + c) * Nn;
    int t = threadIdx.x;
    float s = 0.f;
    for (int i = t; i < Nn; i += 256) { float v = ptr[i]; s += v * v; }
    __shared__ float red[256];
    red[t] = s; __syncthreads();
    for (int st = 128; st > 0; st >>= 1) { if (t < st) red[t] += red[t + st]; __syncthreads(); }
    float scale = 1.0f / fmaxf(sqrtf(red[0]), 1e-12f);
    for (int i = t; i < Nn; i += 256) ptr[i] *= scale;
}

// ---------------------------------------------------------------------------
// Gate stage 2 + final.
// ---------------------------------------------------------------------------
__global__ __launch_bounds__(256) void gate2_kernel(const float* __restrict__ gmid,
                                                    const float* __restrict__ w2,
                                                    const float* __restrict__ b2,
                                                    float* __restrict__ blocksums,
                                                    int out_off) {
    int p = blockIdx.x * 256 + threadIdx.x;
    int b = blockIdx.z;
    float acc = b2[0];
    const float* ib = gmid + (size_t)b * 64 * Nn + p;
    #pragma unroll 8
    for (int ci = 0; ci < 64; ++ci) acc += ib[(size_t)ci * Nn] * w2[ci];
    float g = 1.0f / (1.0f + expf(-acc));
    __shared__ float red[256];
    int t = threadIdx.x;
    red[t] = g; __syncthreads();
    for (int st = 128; st > 0; st >>= 1) { if (t < st) red[t] += red[t + st]; __syncthreads(); }
    if (t == 0) blocksums[out_off + b * 64 + blockIdx.x] = red[0];
}

__global__ void gate_final_kernel(const float* __restrict__ blocksums,
                                  int* __restrict__ dk_out) {
    __shared__ double sred[256];
    int t = threadIdx.x;
    sred[t] = (double)blocksums[t];
    __syncthreads();
    for (int st = 128; st > 0; st >>= 1) { if (t < st) sred[t] += sred[t + st]; __syncthreads(); }
    if (t == 0) {
        double mean = sred[0] / (double)(Bn * Nn);
        float val = 16.0f * (float)mean;
        int dk = (int)val;
        if (dk < 1) dk = 1;
        if (dk > 16) dk = 16;
        *dk_out = dk;
    }
}

// ---------------------------------------------------------------------------
// QK^T partial (f32). grid: (NS, HEADS, Bt).
// ---------------------------------------------------------------------------
__global__ __launch_bounds__(256) void attn_qk_partial_kernel(const float* __restrict__ q,
                                                              const float* __restrict__ k,
                                                              int kstride,
                                                              float* __restrict__ partial) {
    int ns = blockIdx.x, h = blockIdx.y, b = blockIdx.z;
    int t = threadIdx.x;
    int c = t >> 4, d = t & 15;
    __shared__ float qs[16][65];
    __shared__ float ks[16][65];
    const float* qb = q + ((size_t)b * Cc + h * CHh) * Nn;
    const float* kb = k + ((size_t)b * kstride + h * CHh) * Nn;
    float acc = 0.f;
    int nbeg = ns * (Nn / NS);
    for (int n0 = nbeg; n0 < nbeg + (Nn / NS); n0 += 64) {
        for (int idx = t; idx < 1024; idx += 256) {
            int r = idx >> 6, col = idx & 63;
            qs[r][col] = qb[(size_t)r * Nn + n0 + col];
            ks[r][col] = kb[(size_t)r * Nn + n0 + col];
        }
        __syncthreads();
        #pragma unroll
        for (int j = 0; j < 64; ++j) acc += qs[c][j] * ks[d][j];
        __syncthreads();
    }
    partial[(((size_t)(b * HEADS + h)) * NS + ns) * 256 + t] = acc;
}

// reduce + temperature + (optional) fused L2-norm scaling.
__global__ __launch_bounds__(256) void attn_reduce_kernel(const float* __restrict__ partial,
                                                          const float* __restrict__ temp,
                                                          const float* __restrict__ qss,
                                                          const float* __restrict__ kss,
                                                          float* __restrict__ attnp) {
    int bh = blockIdx.x;
    int h = bh % HEADS;
    int t = threadIdx.x;
    const float* pp = partial + (size_t)bh * NS * 256 + t;
    float s = 0.f;
    #pragma unroll 8
    for (int ns = 0; ns < NS; ++ns) s += pp[(size_t)ns * 256];
    float scale = temp[h];
    if (qss != nullptr) {
        int b  = bh / HEADS;
        int cQ = h * CHh + (t >> 4);
        int cK = h * CHh + (t & 15);
        float nq = fmaxf(sqrtf(qss[(size_t)b * Cc + cQ]), 1e-12f);
        float nk = fmaxf(sqrtf(kss[(size_t)b * Cc + cK]), 1e-12f);
        scale = scale / (nq * nk);
    }
    attnp[(size_t)bh * 256 + t] = s * scale;
}

__global__ void topk_softmax_kernel(float* __restrict__ attnp, const int* __restrict__ dkp) {
    int bh = blockIdx.x;
    int c = threadIdx.x;
    if (c >= 16) return;
    float* row = attnp + ((size_t)bh * CHh + c) * CHh;
    float a[16];
    #pragma unroll
    for (int d = 0; d < 16; ++d) a[d] = row[d];
    int dk = *dkp;
    unsigned keep = 0;
    float m = -INFINITY;
    #pragma unroll
    for (int d = 0; d < 16; ++d) {
        int rank = 0;
        #pragma unroll
        for (int j = 0; j < 16; ++j)
            rank += (a[j] > a[d]) || (a[j] == a[d] && j < d);
        if (rank < dk) { keep |= (1u << d); m = fmaxf(m, a[d]); }
    }
    float e[16]; float s = 0.f;
    #pragma unroll
    for (int d = 0; d < 16; ++d) {
        e[d] = (keep >> d & 1u) ? expf(a[d] - m) : 0.f;
        s += e[d];
    }
    float invs = 1.0f / s;
    #pragma unroll
    for (int d = 0; d < 16; ++d) row[d] = e[d] * invs;
}

// attn_v: f32 out (tier-2)
__global__ __launch_bounds__(256) void attn_v_kernel(const float* __restrict__ attnp,
                                                     const float* __restrict__ v,
                                                     float* __restrict__ out) {
    int p = blockIdx.x * 256 + threadIdx.x;
    int cg = blockIdx.y;
    int b = blockIdx.z;
    int h = cg >> 4, cr = cg & 15;
    const float* arow = attnp + (((size_t)b * HEADS + h) * CHh + cr) * CHh;
    const float* vb = v + ((size_t)b * Cc + h * CHh) * Nn + p;
    float acc = 0.f;
    #pragma unroll
    for (int d = 0; d < 16; ++d) acc += arow[d] * vb[(size_t)d * Nn];
    out[((size_t)b * Cc + cg) * Nn + p] = acc;
}

// attn_v: bf16 out.
__global__ __launch_bounds__(256) void attn_v_bf16_kernel(const float* __restrict__ attnp,
                                                          const float* __restrict__ v,
                                                          int vstride, int voff,
                                                          ushort_t* __restrict__ out) {
    int p = blockIdx.x * 256 + threadIdx.x;
    int cg = blockIdx.y;
    int b = blockIdx.z;
    int h = cg >> 4, cr = cg & 15;
    const float* arow = attnp + (((size_t)b * HEADS + h) * CHh + cr) * CHh;
    const float* vb = v + ((size_t)b * vstride + voff + h * CHh) * Nn + p;
    float acc = 0.f;
    #pragma unroll
    for (int d = 0; d < 16; ++d) acc += arow[d] * vb[(size_t)d * Nn];
    out[((size_t)b * Cc + cg) * Nn + p] = f2bf(acc);
}

// ---------------------------------------------------------------------------
// Fused IEL tail v7: shared-u two-stage (exact padding), conflict-free
// 4-px-per-lane LDS pattern, fast tanh, stage(t2) overlapped with outer(t1).
//   u  = conv3x3(t, dw); s = conv3x3(u, dw1/dw2)
//   out = (tanh(s1)+u1) * (tanh(s2)+u2)
// LDS 20672 B. grid: (Hh/16, HID, Bt), block 256.
// ---------------------------------------------------------------------------
__global__ __launch_bounds__(256) void iel_tail_v7_kernel(const ushort_t* __restrict__ Th,
                                                          const float* __restrict__ dww,
                                                          const float* __restrict__ dw1p,
                                                          const float* __restrict__ dw2p,
                                                          ushort_t* __restrict__ PRh) {
    const int gy0 = blockIdx.x * 16;
    const int c   = blockIdx.y;
    const int b   = blockIdx.z;
    const int tid = threadIdx.x;

    __shared__ float ts[20][136];   // 10880 B
    __shared__ float us[18][136];   //  9792 B

    const ushort_t* t1 = Th + ((size_t)b * HID2 + c) * Nn;
    const ushort_t* t2 = Th + ((size_t)b * HID2 + HID + c) * Nn;
    ushort_t* outp = PRh + ((size_t)b * HID + c) * Nn;

    // phase 1: stage t1
    iel7_stage(ts, t1, gy0, tid);
    __syncthreads();
    // phase 2: u1 = conv(t1, dwA)
    iel7_ustage(ts, us, dww + (size_t)c * 9, gy0, tid);
    __syncthreads();
    // phase 3: stage t2 (writes ts) overlapped with outer1 (reads us)
    iel7_stage(ts, t2, gy0, tid);
    float keep[2][4];
    #pragma unroll
    for (int it = 0; it < 2; ++it) {
        int idx = tid + it * 256;
        iel7_outer(us, dw1p + (size_t)c * 9, idx >> 5, idx & 31, keep[it]);
    }
    __syncthreads();
    // phase 4: u2 = conv(t2, dwB)
    iel7_ustage(ts, us, dww + (size_t)(HID + c) * 9, gy0, tid);
    __syncthreads();
    // phase 5: outer2 + multiply + store
    #pragma unroll
    for (int it = 0; it < 2; ++it) {
        int idx = tid + it * 256;
        int r = idx >> 5;
        int s = idx & 31;
        float res[4];
        iel7_outer(us, dw2p + (size_t)c * 9, r, s, res);
        uint2 pk;
        pk.x = (unsigned)f2bf(keep[it][0] * res[0]) | ((unsigned)f2bf(keep[it][1] * res[1]) << 16);
        pk.y = (unsigned)f2bf(keep[it][2] * res[2]) | ((unsigned)f2bf(keep[it][3] * res[3]) << 16);
        *(uint2*)(outp + (gy0 + r) * Wb + 4 * s) = pk;
    }
}

// f32 IEL tail (tier-2 fallback; per-chunk layout).
__global__ __launch_bounds__(256) void iel_tail_f32_kernel(const float* __restrict__ t1p,
                                                           const float* __restrict__ t2p,
                                                           const float* __restrict__ dwA,
                                                           const float* __restrict__ dwB,
                                                           const float* __restrict__ dw1p,
                                                           const float* __restrict__ dw2p,
                                                           float* __restrict__ prod) {
    const int c = blockIdx.y;
    const int tilesx = Wb / 16;
    const int ty0 = (blockIdx.x / tilesx) * 16;
    const int tx0 = (blockIdx.x % tilesx) * 16;
    const int tid = threadIdx.x;

    __shared__ float ts[2][20][24];
    __shared__ float us[2][18][24];

    const float* t1 = t1p + (size_t)c * Nn;
    const float* t2 = t2p + (size_t)c * Nn;

    for (int idx = tid; idx < 400; idx += 256) {
        int i = idx / 20, j = idx % 20;
        int gy = ty0 - 2 + i, gx = tx0 - 2 + j;
        bool ok = (gy >= 0 && gy < Hh && gx >= 0 && gx < Wb);
        ts[0][i][j] = ok ? t1[gy * Wb + gx] : 0.f;
        ts[1][i][j] = ok ? t2[gy * Wb + gx] : 0.f;
    }
    __syncthreads();

    float wA[9], wB[9], w1[9], w2[9];
    #pragma unroll
    for (int k = 0; k < 9; ++k) {
        wA[k] = dwA[c * 9 + k];
        wB[k] = dwB[c * 9 + k];
        w1[k] = dw1p[c * 9 + k];
        w2[k] = dw2p[c * 9 + k];
    }

    for (int idx = tid; idx < 324; idx += 256) {
        int i = idx / 18, j = idx % 18;
        int gy = ty0 - 1 + i, gx = tx0 - 1 + j;
        float a0 = 0.f, a1 = 0.f;
        if (gy >= 0 && gy < Hh && gx >= 0 && gx < Wb) {
            #pragma unroll
            for (int dy = 0; dy < 3; ++dy)
                #pragma unroll
                for (int dx = 0; dx < 3; ++dx) {
                    a0 += wA[dy * 3 + dx] * ts[0][i + dy][j + dx];
                    a1 += wB[dy * 3 + dx] * ts[1][i + dy][j + dx];
                }
        }
        us[0][i][j] = a0;
        us[1][i][j] = a1;
    }
    __syncthreads();

    int ty = tid >> 4, tx = tid & 15;
    float c1 = us[0][ty + 1][tx + 1];
    float c2 = us[1][ty + 1][tx + 1];
    float s1 = 0.f, s2 = 0.f;
    #pragma unroll
    for (int dy = 0; dy < 3; ++dy)
        #pragma unroll
        for (int dx = 0; dx < 3; ++dx) {
            s1 += w1[dy * 3 + dx] * us[0][ty + dy][tx + dx];
            s2 += w2[dy * 3 + dx] * us[1][ty + dy][tx + dx];
        }
    float x1t = tanhf(s1) + c1;
    float x2t = tanhf(s2) + c2;
    prod[(size_t)c * Nn + (ty0 + ty) * Wb + (tx0 + tx)] = x1t * x2t;
}

// ---------------------------------------------------------------------------
// Host launcher
// ---------------------------------------------------------------------------
extern "C" void kernel_launch(void* const* d_in, const int* in_sizes, int n_in,
                              void* d_out, int out_size, void* d_ws, size_t ws_size,
                              hipStream_t stream) {
    const float* x      = (const float*)d_in[0];
    const float* y      = (const float*)d_in[1];
    const float* ln_w   = (const float*)d_in[2];
    const float* ln_b   = (const float*)d_in[3];
    const float* temp   = (const float*)d_in[4];
    const float* q_w    = (const float*)d_in[5];
    const float* qdw_w  = (const float*)d_in[6];
    const float* kv_w   = (const float*)d_in[7];
    const float* kvdw_w = (const float*)d_in[8];
    const float* po_w   = (const float*)d_in[9];
    const float* g1_w   = (const float*)d_in[10];
    const float* g1_b   = (const float*)d_in[11];
    const float* g2_w   = (const float*)d_in[12];
    const float* g2_b   = (const float*)d_in[13];
    const float* pin_w  = (const float*)d_in[14];
    const float* dw_w   = (const float*)d_in[15];
    const float* dw1_w  = (const float*)d_in[16];
    const float* dw2_w  = (const float*)d_in[17];
    const float* pout_w = (const float*)d_in[18];
    float* out = (float*)d_out;

    // smalls in first 1 MiB
    char* ws = (char*)d_ws;
    float* attn      = (float*)ws;                        // 32 KB
    float* blocksums = (float*)(ws + 32768);              // 1 KB
    int*   dk        = (int*)(ws + 33792);
    ushort_t* qWh  = (ushort_t*)(ws + 34816);             // 128x128
    ushort_t* kvWh = qWh + 16384;                         // 256x128
    ushort_t* poWh = kvWh + 32768;                        // 128x128
    ushort_t* g1Wh = poWh + 16384;                        // 64x128
    ushort_t* Wh1  = g1Wh + 8192;                         // 704x128
    ushort_t* Wh2  = Wh1 + (size_t)MPAD * Cc;             // 128x352
    float* qss = (float*)(ws + 458752);                   // [Bn][128] sumsq(q)
    float* kss = (float*)(ws + 460800);                   // [Bn][128] sumsq(k)
    float* pool    = (float*)(ws + (1u << 20));

    const size_t CN    = (size_t)Cc * Nn;
    const size_t SLOT1 = (size_t)Bn * CN;
    const size_t TIER1_NEED = 65536 + 6 * SLOT1 * 4;

    dim3 blk(256);
    const int PGX = Nn / 1024;

    if (ws_size >= TIER1_NEED) {
        // ---- buffers ----
        float* S3 = pool;                                  // q2 f32 [B][128][Nn]
        float* S4 = pool + 8 * 1024 * 1024;                // k2+v2 f32 [B][256][Nn]
        ushort_t* XNh  = (ushort_t*)(pool + 24 * 1024 * 1024);
        ushort_t* YNh  = XNh + Bn * CN;
        ushort_t* KV1h = YNh + Bn * CN;
        ushort_t* Q1h  = KV1h + 2 * Bn * CN;
        float* gmid    = (float*)Q1h;
        float* partial = gmid;
        ushort_t* AOh  = XNh;

        wconv_pad_rows_kernel<<<dim3(64), blk, 0, stream>>>(q_w, qWh, 128, Cc);
        wconv_pad_rows_kernel<<<dim3(128), blk, 0, stream>>>(kv_w, kvWh, 256, Cc);
        wconv_pad_rows_kernel<<<dim3(64), blk, 0, stream>>>(po_w, poWh, 128, Cc);
        wconv_pad_rows_kernel<<<dim3(32), blk, 0, stream>>>(g1_w, g1Wh, 64, Cc);
        wconv_pad_rows_kernel<<<dim3(MPAD * Cc / 256), blk, 0, stream>>>(pin_w, Wh1, HID2, Cc);
        wconv_pad_cols_kernel<<<dim3(Cc * KPAD2 / 256), blk, 0, stream>>>(pout_w, Wh2, HID, KPAD2);
        zero_f32_kernel<<<dim3(4), blk, 0, stream>>>(qss, 2 * Bn * Cc);  // qss+kss contiguous

        // ---- Phase A ----
        ln_bf16_kernel<<<dim3(Nn / 256, 1, Bn), blk, 0, stream>>>(x, ln_w, ln_b, XNh);
        ln_bf16_kernel<<<dim3(Nn / 256, 1, Bn), blk, 0, stream>>>(y, ln_w, ln_b, YNh);

        gemm_bf16_kernel<<<dim3(Nn / 128, 2, Bn), blk, 0, stream>>>(
            XNh, qWh, nullptr, nullptr, nullptr, Q1h, Cc, Cc, Cc, 0);
        dw3x3_bf16_v3_kernel<<<dim3(Hh / 16, Cc, Bn), blk, 0, stream>>>(
            Q1h, qdw_w, S3, Cc, qss, Cc);

        gemm_bf16_kernel<<<dim3(Nn / 128, 4, Bn), blk, 0, stream>>>(
            YNh, kvWh, nullptr, nullptr, nullptr, KV1h, Cc, Cc, 2 * Cc, 0);
        dw3x3_bf16_v3_kernel<<<dim3(Hh / 16, 2 * Cc, Bn), blk, 0, stream>>>(
            KV1h, kvdw_w, S4, 2 * Cc, kss, Cc);

        gemm_bf16_kernel<<<dim3(Nn / 128, 1, Bn), blk, 0, stream>>>(
            XNh, g1Wh, g1_b, nullptr, gmid, nullptr, Cc, Cc, 64, 1);
        gate2_kernel<<<dim3(Nn / 256, 1, Bn), blk, 0, stream>>>(gmid, g2_w, g2_b, blocksums, 0);
        gate_final_kernel<<<dim3(1), blk, 0, stream>>>(blocksums, dk);

        // L2 norms folded into attn_reduce via qss/kss (no l2norm passes).
        attn_qk_partial_kernel<<<dim3(NS, HEADS, Bn), blk, 0, stream>>>(S3, S4, 2 * Cc, partial);
        attn_reduce_kernel<<<dim3(Bn * HEADS), blk, 0, stream>>>(partial, temp, qss, kss, attn);
        topk_softmax_kernel<<<dim3(Bn * HEADS), dim3(16), 0, stream>>>(attn, dk);
        attn_v_bf16_kernel<<<dim3(Nn / 256, Cc, Bn), blk, 0, stream>>>(
            attn, S4, 2 * Cc, Cc, AOh);

        gemm_bf16_kernel<<<dim3(Nn / 128, 2, Bn), blk, 0, stream>>>(
            AOh, poWh, nullptr, x, out, nullptr, Cc, Cc, Cc, 0);

        // ---- Phase B ----
        ushort_t* ZNh = (ushort_t*)pool;
        ushort_t* Th  = ZNh + Bn * CN;
        ushort_t* PRh = Th + (size_t)Bn * HID2 * Nn;

        ln_bf16_kernel<<<dim3(Nn / 256, 1, Bn), blk, 0, stream>>>(out, ln_w, ln_b, ZNh);

        gemm_bf16_kernel<<<dim3(Nn / 128, MPAD / 64, Bn), blk, 0, stream>>>(
            ZNh, Wh1, nullptr, nullptr, nullptr, Th, Cc, Cc, HID2, 0);

        iel_tail_v7_kernel<<<dim3(Hh / 16, HID, Bn), blk, 0, stream>>>(
            Th, dw_w, dw1_w, dw2_w, PRh);

        gemm_bf16_kernel<<<dim3(Nn / 128, 2, Bn), blk, 0, stream>>>(
            PRh, Wh2, nullptr, out, out, nullptr, HID, KPAD2, Cc, 0);
    } else {
        // ================= Tier 2: per-batch f32 fallback ===================
        float* s0 = pool;
        float* s1 = pool + 1 * CN;
        float* s2 = pool + 2 * CN;
        float* s3 = pool + 3 * CN;
        float* s4 = pool + 4 * CN;
        float* s5 = pool + 5 * CN;

        for (int b = 0; b < Bn; ++b) {
            const float* xb = x + (size_t)b * CN;
            ln_kernel<<<dim3(Nn / 256, 1, 1), blk, 0, stream>>>(xb, ln_w, ln_b, s0);
            conv1x1v_kernel<4><<<dim3(PGX, 16, 1), blk, 0, stream>>>(
                s0, g1_w, Cc, g1_b, nullptr, s1, Cc, 64, 1);
            gate2_kernel<<<dim3(Nn / 256, 1, 1), blk, 0, stream>>>(
                s1, g2_w, g2_b, blocksums, b * 64);
        }
        gate_final_kernel<<<dim3(1), blk, 0, stream>>>(blocksums, dk);

        for (int b = 0; b < Bn; ++b) {
            const float* xb = x + (size_t)b * CN;
            const float* yb = y + (size_t)b * CN;
            float* outb = out + (size_t)b * CN;
            float* attnb = attn + (size_t)b * HEADS * CHh * CHh;

            ln_kernel<<<dim3(Nn / 256, 1, 1), blk, 0, stream>>>(xb, ln_w, ln_b, s0);
            ln_kernel<<<dim3(Nn / 256, 1, 1), blk, 0, stream>>>(yb, ln_w, ln_b, s1);

            conv1x1v_kernel<8><<<dim3(PGX, 16, 1), blk, 0, stream>>>(
                s0, q_w, Cc, nullptr, nullptr, s2, Cc, Cc, 0);
            dw3x3_kernel<<<dim3(Nn / 256, Cc, 1), blk, 0, stream>>>(s2, qdw_w, s3, Cc);
            l2norm_kernel<<<dim3(Cc, 1, 1), blk, 0, stream>>>(s3, Cc);

            conv1x1v_kernel<8><<<dim3(PGX, 16, 1), blk, 0, stream>>>(
                s1, kv_w, Cc, nullptr, nullptr, s2, Cc, Cc, 0);
            dw3x3_kernel<<<dim3(Nn / 256, Cc, 1), blk, 0, stream>>>(s2, kvdw_w, s4, Cc);
            l2norm_kernel<<<dim3(Cc, 1, 1), blk, 0, stream>>>(s4, Cc);

            conv1x1v_kernel<8><<<dim3(PGX, 16, 1), blk, 0, stream>>>(
                s1, kv_w + 128 * 128, Cc, nullptr, nullptr, s2, Cc, Cc, 0);
            dw3x3_kernel<<<dim3(Nn / 256, Cc, 1), blk, 0, stream>>>(s2, kvdw_w + 128 * 9, s5, Cc);

            attn_qk_partial_kernel<<<dim3(NS, HEADS, 1), blk, 0, stream>>>(s3, s4, Cc, s2);
            attn_reduce_kernel<<<dim3(HEADS), blk, 0, stream>>>(s2, temp, nullptr, nullptr, attnb);
            topk_softmax_kernel<<<dim3(HEADS), dim3(16), 0, stream>>>(attnb, dk);
            attn_v_kernel<<<dim3(Nn / 256, Cc, 1), blk, 0, stream>>>(attnb, s5, s2);

            conv1x1v_kernel<8><<<dim3(PGX, 16, 1), blk, 0, stream>>>(
                s2, po_w, Cc, nullptr, xb, outb, Cc, Cc, 0);
        }

        const int CHUNK = 170;
        const size_t TCH = (size_t)CHUNK * Nn;
        float* zn   = pool;
        float* T1   = pool + CN;
        float* T2   = T1 + TCH;
        float* prod = T2 + TCH;
        for (int b = 0; b < Bn; ++b) {
            float* outb = out + (size_t)b * CN;
            ln_kernel<<<dim3(Nn / 256, 1, 1), blk, 0, stream>>>(outb, ln_w, ln_b, zn);
            for (int c0 = 0; c0 < HID; c0 += CHUNK) {
                conv1x1v_kernel<20><<<dim3(PGX, 9, 1), blk, 0, stream>>>(
                    zn, pin_w + (size_t)c0 * Cc, Cc, nullptr, nullptr, T1, Cc, CHUNK, 0);
                conv1x1v_kernel<20><<<dim3(PGX, 9, 1), blk, 0, stream>>>(
                    zn, pin_w + (size_t)(HID + c0) * Cc, Cc, nullptr, nullptr, T2, Cc, CHUNK, 0);
                iel_tail_f32_kernel<<<dim3(64, CHUNK, 1), blk, 0, stream>>>(
                    T1, T2, dw_w + c0 * 9, dw_w + (HID + c0) * 9,
                    dw1_w + c0 * 9, dw2_w + c0 * 9, prod);
                conv1x1v_kernel<8><<<dim3(PGX, 16, 1), blk, 0, stream>>>(
                    prod, pout_w + c0, HID, nullptr, outb, outb, CHUNK, Cc, 0);
            }
        }
    }
}